// Round 1
// baseline (336.778 us; speedup 1.0000x reference)
//
#include <hip/hip_runtime.h>

#define IN_FEATS 602
#define N_HIDDEN 256
#define N_CLASSES 41
#define N_SRC0 292864
#define N_DST0 11264
#define N_DST1 1024
#define FAN0 25
#define FAN1 10
#define KTOT (2*IN_FEATS)   // 1204: K-concat of [x_self | h_neigh]

// ---------------------------------------------------------------------------
// Kernel 1: h_neigh0[d][f] = mean_{n<25} x[idx0[d*25+n]][f]
// One block per dst row; 256 threads stride the 602 features (coalesced).
// ---------------------------------------------------------------------------
__global__ __launch_bounds__(256) void agg0_kernel(
    const float* __restrict__ x,
    const int* __restrict__ idx,
    float* __restrict__ hn)
{
    const int d = blockIdx.x;
    __shared__ int sidx[FAN0];
    if (threadIdx.x < FAN0) sidx[threadIdx.x] = idx[d * FAN0 + threadIdx.x];
    __syncthreads();

    for (int f = threadIdx.x; f < IN_FEATS; f += 256) {
        float acc = 0.f;
        #pragma unroll
        for (int n = 0; n < FAN0; ++n)
            acc += x[(size_t)sidx[n] * IN_FEATS + f];
        hn[(size_t)d * IN_FEATS + f] = acc * (1.0f / FAN0);
    }
}

// ---------------------------------------------------------------------------
// Kernel 2: h = relu([x_self | hn0] @ [Wself0; Wneigh0] + b0)
// M=11264, N=256, K=1204. fp32 tiled GEMM: 64x64 tile, BK=16, 256 thr, 4x4/thr.
// ---------------------------------------------------------------------------
#define BM 64
#define BN 64
#define BK 16

__global__ __launch_bounds__(256) void gemm0_kernel(
    const float* __restrict__ x,       // [N_SRC0][602] (rows < 11264 used)
    const float* __restrict__ hn,      // [11264][602]
    const float* __restrict__ Wself,   // [602][256]
    const float* __restrict__ Wneigh,  // [602][256]
    const float* __restrict__ b,       // [256]
    float* __restrict__ h)             // [11264][256]
{
    __shared__ float As[BM][BK + 1];
    __shared__ float Bs[BK][BN];

    const int tid = threadIdx.x;
    const int tx = tid & 15;       // 0..15 -> N
    const int ty = tid >> 4;       // 0..15 -> M
    const int m0 = blockIdx.y * BM;
    const int n0 = blockIdx.x * BN;

    // A loader: row ar (0..63), 4 consecutive k at ac
    const int ar = tid >> 2;
    const int ac = (tid & 3) * 4;
    // B loader: k-row br (0..15), 4 consecutive n at bc
    const int br = tid >> 4;
    const int bc = (tid & 15) * 4;

    float acc[4][4] = {};

    const int ntiles = (KTOT + BK - 1) / BK;  // 76, last tile 4 valid
    for (int t = 0; t < ntiles; ++t) {
        const int k0 = t * BK;

        #pragma unroll
        for (int i = 0; i < 4; ++i) {
            const int k = k0 + ac + i;
            float v = 0.f;
            if (k < KTOT) {
                if (k < IN_FEATS)
                    v = x[(size_t)(m0 + ar) * IN_FEATS + k];
                else
                    v = hn[(size_t)(m0 + ar) * IN_FEATS + (k - IN_FEATS)];
            }
            As[ar][ac + i] = v;
        }
        {
            const int k = k0 + br;
            float4 v = make_float4(0.f, 0.f, 0.f, 0.f);
            if (k < KTOT) {
                const float* W = (k < IN_FEATS) ? Wself : Wneigh;
                const int kc = (k < IN_FEATS) ? k : k - IN_FEATS;
                v = *(const float4*)&W[(size_t)kc * N_HIDDEN + n0 + bc];
            }
            *(float4*)&Bs[br][bc] = v;
        }
        __syncthreads();

        #pragma unroll
        for (int kk = 0; kk < BK; ++kk) {
            const float a0 = As[ty * 4 + 0][kk];
            const float a1 = As[ty * 4 + 1][kk];
            const float a2 = As[ty * 4 + 2][kk];
            const float a3 = As[ty * 4 + 3][kk];
            const float4 bq = *(const float4*)&Bs[kk][tx * 4];
            acc[0][0] = fmaf(a0, bq.x, acc[0][0]);
            acc[0][1] = fmaf(a0, bq.y, acc[0][1]);
            acc[0][2] = fmaf(a0, bq.z, acc[0][2]);
            acc[0][3] = fmaf(a0, bq.w, acc[0][3]);
            acc[1][0] = fmaf(a1, bq.x, acc[1][0]);
            acc[1][1] = fmaf(a1, bq.y, acc[1][1]);
            acc[1][2] = fmaf(a1, bq.z, acc[1][2]);
            acc[1][3] = fmaf(a1, bq.w, acc[1][3]);
            acc[2][0] = fmaf(a2, bq.x, acc[2][0]);
            acc[2][1] = fmaf(a2, bq.y, acc[2][1]);
            acc[2][2] = fmaf(a2, bq.z, acc[2][2]);
            acc[2][3] = fmaf(a2, bq.w, acc[2][3]);
            acc[3][0] = fmaf(a3, bq.x, acc[3][0]);
            acc[3][1] = fmaf(a3, bq.y, acc[3][1]);
            acc[3][2] = fmaf(a3, bq.z, acc[3][2]);
            acc[3][3] = fmaf(a3, bq.w, acc[3][3]);
        }
        __syncthreads();
    }

    #pragma unroll
    for (int i = 0; i < 4; ++i) {
        const int row = m0 + ty * 4 + i;
        #pragma unroll
        for (int j = 0; j < 4; ++j) {
            const int col = n0 + tx * 4 + j;
            float v = acc[i][j] + b[col];
            v = fmaxf(v, 0.f);
            h[(size_t)row * N_HIDDEN + col] = v;
        }
    }
}

// ---------------------------------------------------------------------------
// Kernel 3: h_neigh1[d][f] = mean_{n<10} h[idx1[d*10+n]][f]
// ---------------------------------------------------------------------------
__global__ __launch_bounds__(256) void agg1_kernel(
    const float* __restrict__ h,
    const int* __restrict__ idx,
    float* __restrict__ hn)
{
    const int d = blockIdx.x;
    __shared__ int sidx[FAN1];
    if (threadIdx.x < FAN1) sidx[threadIdx.x] = idx[d * FAN1 + threadIdx.x];
    __syncthreads();

    const int f = threadIdx.x;  // 256 threads == N_HIDDEN
    float acc = 0.f;
    #pragma unroll
    for (int n = 0; n < FAN1; ++n)
        acc += h[(size_t)sidx[n] * N_HIDDEN + f];
    hn[(size_t)d * N_HIDDEN + f] = acc * (1.0f / FAN1);
}

// ---------------------------------------------------------------------------
// Kernel 4: out[d][n] = h[d] @ Wself1 + hn1[d] @ Wneigh1 + b1
// One block (64 thr) per dst row; rows staged in LDS; threads 0..40 compute.
// ---------------------------------------------------------------------------
__global__ __launch_bounds__(64) void layer1_kernel(
    const float* __restrict__ h,
    const float* __restrict__ hn1,
    const float* __restrict__ Wself,   // [256][41]
    const float* __restrict__ Wneigh,  // [256][41]
    const float* __restrict__ b,       // [41]
    float* __restrict__ out)           // [1024][41]
{
    const int d = blockIdx.x;
    __shared__ float hd[N_HIDDEN];
    __shared__ float hn[N_HIDDEN];
    for (int k = threadIdx.x; k < N_HIDDEN; k += 64) {
        hd[k] = h[(size_t)d * N_HIDDEN + k];
        hn[k] = hn1[(size_t)d * N_HIDDEN + k];
    }
    __syncthreads();

    for (int n = threadIdx.x; n < N_CLASSES; n += 64) {
        float acc = b[n];
        #pragma unroll 8
        for (int k = 0; k < N_HIDDEN; ++k)
            acc += hd[k] * Wself[k * N_CLASSES + n]
                 + hn[k] * Wneigh[k * N_CLASSES + n];
        out[(size_t)d * N_CLASSES + n] = acc;
    }
}

// ---------------------------------------------------------------------------
extern "C" void kernel_launch(void* const* d_in, const int* in_sizes, int n_in,
                              void* d_out, int out_size, void* d_ws, size_t ws_size,
                              hipStream_t stream) {
    const float* x       = (const float*)d_in[0];
    const float* Wself0  = (const float*)d_in[1];
    const float* Wneigh0 = (const float*)d_in[2];
    const float* b0      = (const float*)d_in[3];
    const float* Wself1  = (const float*)d_in[4];
    const float* Wneigh1 = (const float*)d_in[5];
    const float* b1      = (const float*)d_in[6];
    const int*   idx0    = (const int*)d_in[7];
    const int*   idx1    = (const int*)d_in[8];
    float* out = (float*)d_out;

    // workspace layout (f32): hn0[11264*602] | h[11264*256] | hn1[1024*256]
    // total ~39.7 MB
    float* hn0 = (float*)d_ws;
    float* h   = hn0 + (size_t)N_DST0 * IN_FEATS;
    float* hn1 = h   + (size_t)N_DST0 * N_HIDDEN;

    agg0_kernel<<<N_DST0, 256, 0, stream>>>(x, idx0, hn0);
    gemm0_kernel<<<dim3(N_HIDDEN / BN, N_DST0 / BM), 256, 0, stream>>>(
        x, hn0, Wself0, Wneigh0, b0, h);
    agg1_kernel<<<N_DST1, 256, 0, stream>>>(h, idx1, hn1);
    layer1_kernel<<<N_DST1, 64, 0, stream>>>(h, hn1, Wself1, Wneigh1, b1, out);
}

// Round 2
// 228.036 us; speedup vs baseline: 1.4769x; 1.4769x over previous
//
#include <hip/hip_runtime.h>
#include <hip/hip_bf16.h>

#define IN_FEATS 602
#define N_HIDDEN 256
#define N_CLASSES 41
#define N_SRC0 292864
#define N_DST0 11264
#define N_DST1 1024
#define FAN0 25
#define FAN1 10
#define KPAD 1216            // 1204 rounded up to multiple of 32

typedef __attribute__((ext_vector_type(4))) float f32x4;
typedef __attribute__((ext_vector_type(8))) short bf16x8;   // 8 bf16 = 4 VGPRs

// ---------------------------------------------------------------------------
// Kernel 1: build A[d] = [ bf16(x[d]) | bf16(mean_{25} x[idx]) | 0-pad ]
// A is [N_DST0][KPAD] bf16. One block per dst row.
// ---------------------------------------------------------------------------
__global__ __launch_bounds__(256) void agg0_kernel(
    const float* __restrict__ x,
    const int* __restrict__ idx,
    __hip_bfloat16* __restrict__ A)
{
    const int d = blockIdx.x;
    __shared__ int sidx[FAN0];
    if (threadIdx.x < FAN0) sidx[threadIdx.x] = idx[d * FAN0 + threadIdx.x];
    __syncthreads();

    __hip_bfloat16* Arow = A + (size_t)d * KPAD;
    const float* xs = x + (size_t)d * IN_FEATS;

    for (int f = threadIdx.x; f < IN_FEATS; f += 256) {
        float acc = 0.f;
        #pragma unroll
        for (int n = 0; n < FAN0; ++n)
            acc += x[(size_t)sidx[n] * IN_FEATS + f];
        Arow[f]            = __float2bfloat16(xs[f]);
        Arow[IN_FEATS + f] = __float2bfloat16(acc * (1.0f / FAN0));
    }
    if (threadIdx.x < KPAD - 2 * IN_FEATS)   // 12 pad cols
        Arow[2 * IN_FEATS + threadIdx.x] = __float2bfloat16(0.f);
}

// ---------------------------------------------------------------------------
// Kernel 2: Wt[n][k] = bf16( k<602 ? Wself0[k][n] : k<1204 ? Wneigh0[k-602][n] : 0 )
// Wt is [N_HIDDEN][KPAD] bf16 (B-operand pre-transposed, K-major per row).
// 32x32 LDS tile transpose; grid (KPAD/32, N_HIDDEN/32).
// ---------------------------------------------------------------------------
__global__ __launch_bounds__(256) void wprep_kernel(
    const float* __restrict__ Ws,
    const float* __restrict__ Wn,
    __hip_bfloat16* __restrict__ Wt)
{
    __shared__ float tile[32][33];
    const int k0 = blockIdx.x * 32, n0 = blockIdx.y * 32;
    const int tx = threadIdx.x & 31, ty = threadIdx.x >> 5;   // 32 x 8

    #pragma unroll
    for (int i = 0; i < 4; ++i) {
        const int k = k0 + ty + i * 8;
        const int n = n0 + tx;
        float v = 0.f;
        if (k < IN_FEATS)            v = Ws[(size_t)k * N_HIDDEN + n];
        else if (k < 2 * IN_FEATS)   v = Wn[(size_t)(k - IN_FEATS) * N_HIDDEN + n];
        tile[ty + i * 8][tx] = v;
    }
    __syncthreads();
    #pragma unroll
    for (int i = 0; i < 4; ++i) {
        const int n = n0 + ty + i * 8;
        const int k = k0 + tx;
        Wt[(size_t)n * KPAD + k] = __float2bfloat16(tile[tx][ty + i * 8]);
    }
}

// ---------------------------------------------------------------------------
// Kernel 3: h = relu(A @ Wt^T + b0)   via bf16 MFMA, f32 accumulate.
// M=11264, N=256, K=1216. 64x64 tile, BK=32, 4 waves each computing 32x32.
// LDS rows padded to 40 bf16 (80 B) -> 2-way bank aliasing only (free).
// Both A and B fragments use contiguous 8-bf16 per lane (k = (lane>>4)*8+j),
// consistent on both operands => dot over K is correct (m97 pattern).
// ---------------------------------------------------------------------------
#define LDSW 40

__global__ __launch_bounds__(256) void gemm0_mfma(
    const __hip_bfloat16* __restrict__ A,     // [N_DST0][KPAD]
    const __hip_bfloat16* __restrict__ Wt,    // [N_HIDDEN][KPAD]
    const float* __restrict__ bias,           // [256]
    float* __restrict__ h)                    // [N_DST0][256]
{
    __shared__ __hip_bfloat16 As[64 * LDSW];
    __shared__ __hip_bfloat16 Bs[64 * LDSW];

    const int tid  = threadIdx.x;
    const int lane = tid & 63;
    const int wave = tid >> 6;
    const int wm = wave >> 1, wn = wave & 1;    // 2x2 waves of 32x32
    const int g = lane >> 4, r = lane & 15;
    const int m0 = blockIdx.y * 64, n0 = blockIdx.x * 64;

    const int srow = tid >> 2;                  // 0..63
    const int scol = (tid & 3) * 8;             // 0,8,16,24 (bf16 elems)

    const size_t a_off = (size_t)(m0 + srow) * KPAD + scol;
    const size_t b_off = (size_t)(n0 + srow) * KPAD + scol;

    f32x4 acc[2][2] = {};

    for (int k0 = 0; k0 < KPAD; k0 += 32) {
        *(float4*)&As[srow * LDSW + scol] = *(const float4*)&A[a_off + k0];
        *(float4*)&Bs[srow * LDSW + scol] = *(const float4*)&Wt[b_off + k0];
        __syncthreads();

        const bf16x8 af0 = *(const bf16x8*)&As[(wm * 32 +      r) * LDSW + g * 8];
        const bf16x8 af1 = *(const bf16x8*)&As[(wm * 32 + 16 + r) * LDSW + g * 8];
        const bf16x8 bf0 = *(const bf16x8*)&Bs[(wn * 32 +      r) * LDSW + g * 8];
        const bf16x8 bf1 = *(const bf16x8*)&Bs[(wn * 32 + 16 + r) * LDSW + g * 8];

        acc[0][0] = __builtin_amdgcn_mfma_f32_16x16x32_bf16(af0, bf0, acc[0][0], 0, 0, 0);
        acc[0][1] = __builtin_amdgcn_mfma_f32_16x16x32_bf16(af0, bf1, acc[0][1], 0, 0, 0);
        acc[1][0] = __builtin_amdgcn_mfma_f32_16x16x32_bf16(af1, bf0, acc[1][0], 0, 0, 0);
        acc[1][1] = __builtin_amdgcn_mfma_f32_16x16x32_bf16(af1, bf1, acc[1][1], 0, 0, 0);
        __syncthreads();
    }

    // C/D layout (m89-verified): col = lane&15, row = (lane>>4)*4 + j
    #pragma unroll
    for (int mh = 0; mh < 2; ++mh)
        #pragma unroll
        for (int nh = 0; nh < 2; ++nh) {
            const int col = n0 + wn * 32 + nh * 16 + r;
            const float bv = bias[col];
            #pragma unroll
            for (int j = 0; j < 4; ++j) {
                const int row = m0 + wm * 32 + mh * 16 + g * 4 + j;
                const float v = acc[mh][nh][j] + bv;
                h[(size_t)row * N_HIDDEN + col] = fmaxf(v, 0.f);
            }
        }
}

// ---------------------------------------------------------------------------
// Kernel 4 (fused agg1 + layer1):
// out[d] = h[d] @ Wself1 + (mean_{10} h[idx1]) @ Wneigh1 + b1     (f32)
// One 64-thread block per dst row.
// ---------------------------------------------------------------------------
__global__ __launch_bounds__(64) void tail_kernel(
    const float* __restrict__ h,
    const int* __restrict__ idx1,
    const float* __restrict__ Ws,     // [256][41]
    const float* __restrict__ Wn,     // [256][41]
    const float* __restrict__ b,      // [41]
    float* __restrict__ out)          // [1024][41]
{
    const int d = blockIdx.x;
    __shared__ float hd[N_HIDDEN];
    __shared__ float hn[N_HIDDEN];
    __shared__ int sidx[FAN1];
    if (threadIdx.x < FAN1) sidx[threadIdx.x] = idx1[d * FAN1 + threadIdx.x];
    __syncthreads();

    for (int k = threadIdx.x; k < N_HIDDEN; k += 64) {
        hd[k] = h[(size_t)d * N_HIDDEN + k];
        float a = 0.f;
        #pragma unroll
        for (int i = 0; i < FAN1; ++i)
            a += h[(size_t)sidx[i] * N_HIDDEN + k];
        hn[k] = a * (1.0f / FAN1);
    }
    __syncthreads();

    if (threadIdx.x < N_CLASSES) {
        const int n = threadIdx.x;
        float a0 = b[n], a1 = 0.f, a2 = 0.f, a3 = 0.f;
        #pragma unroll 4
        for (int k = 0; k < N_HIDDEN; k += 4) {
            a0 += hd[k + 0] * Ws[(k + 0) * N_CLASSES + n] + hn[k + 0] * Wn[(k + 0) * N_CLASSES + n];
            a1 += hd[k + 1] * Ws[(k + 1) * N_CLASSES + n] + hn[k + 1] * Wn[(k + 1) * N_CLASSES + n];
            a2 += hd[k + 2] * Ws[(k + 2) * N_CLASSES + n] + hn[k + 2] * Wn[(k + 2) * N_CLASSES + n];
            a3 += hd[k + 3] * Ws[(k + 3) * N_CLASSES + n] + hn[k + 3] * Wn[(k + 3) * N_CLASSES + n];
        }
        out[(size_t)d * N_CLASSES + n] = a0 + a1 + a2 + a3;
    }
}

// ---------------------------------------------------------------------------
extern "C" void kernel_launch(void* const* d_in, const int* in_sizes, int n_in,
                              void* d_out, int out_size, void* d_ws, size_t ws_size,
                              hipStream_t stream) {
    const float* x       = (const float*)d_in[0];
    const float* Wself0  = (const float*)d_in[1];
    const float* Wneigh0 = (const float*)d_in[2];
    const float* b0      = (const float*)d_in[3];
    const float* Wself1  = (const float*)d_in[4];
    const float* Wneigh1 = (const float*)d_in[5];
    const float* b1      = (const float*)d_in[6];
    const int*   idx0    = (const int*)d_in[7];
    const int*   idx1    = (const int*)d_in[8];
    float* out = (float*)d_out;

    // ws layout: A bf16 [11264*1216] | Wt bf16 [256*1216] | h f32 [11264*256]
    __hip_bfloat16* Abf = (__hip_bfloat16*)d_ws;
    __hip_bfloat16* Wt  = Abf + (size_t)N_DST0 * KPAD;
    float*          h   = (float*)(Wt + (size_t)N_HIDDEN * KPAD);

    wprep_kernel<<<dim3(KPAD / 32, N_HIDDEN / 32), 256, 0, stream>>>(Wself0, Wneigh0, Wt);
    agg0_kernel<<<N_DST0, 256, 0, stream>>>(x, idx0, Abf);
    gemm0_mfma<<<dim3(N_HIDDEN / 64, N_DST0 / 64), 256, 0, stream>>>(Abf, Wt, b0, h);
    tail_kernel<<<N_DST1, 64, 0, stream>>>(h, idx1, Wself1, Wneigh1, b1, out);
}